// Round 1
// baseline (56.127 us; speedup 1.0000x reference)
//
#include <hip/hip_runtime.h>

#define N_NODES   200000
#define NBLK      256
#define TPB       512          // 8 waves
#define PASSES    4            // ceil(200000 / (256 blocks * 256 nodes))
#define LDS_BYTES 131072       // 32K W1 + 32K W2 + 8 waves * 8K h1

typedef __attribute__((ext_vector_type(8))) short short8;   // bf16x8 fragment
typedef __attribute__((ext_vector_type(4))) float f32x4;

__device__ __forceinline__ unsigned short f2bf(float f) {
  // round-to-nearest-even fp32 -> bf16 bits
  unsigned int u = __builtin_bit_cast(unsigned int, f);
  u += 0x7FFFu + ((u >> 16) & 1u);
  return (unsigned short)(u >> 16);
}

__device__ __forceinline__ f32x4 mfma16(short8 a, short8 b, f32x4 c) {
  return __builtin_amdgcn_mfma_f32_16x16x32_bf16(a, b, c, 0, 0, 0);
}

__global__ __launch_bounds__(TPB, 2) void gcn_main(
    const float* __restrict__ x,  const float* __restrict__ W1,
    const float* __restrict__ b1, const float* __restrict__ W2,
    const float* __restrict__ b2, float* __restrict__ sums)
{
  extern __shared__ char lds[];
  char* const ldsW0 = lds;            // W1 bf16, swizzled, 32 KB
  char* const ldsW1 = lds + 32768;    // W2 bf16, swizzled, 32 KB
  const int tid  = threadIdx.x;
  const int lane = tid & 63;
  const int wid  = tid >> 6;
  char* const h1 = lds + 65536 + wid * 8192;   // per-wave [32][128] bf16, swizzled

  // ---- stage W1, W2 as swizzled bf16 ----
  {
    const float* Ws[2] = { W1, W2 };
    char* Ld[2] = { ldsW0, ldsW1 };
    #pragma unroll
    for (int wsel = 0; wsel < 2; ++wsel) {
      #pragma unroll
      for (int i = 0; i < 4; ++i) {
        int c   = tid + i * TPB;       // chunk 0..2047
        int row = c >> 4, kc = c & 15;
        const f32x4* src = (const f32x4*)(Ws[wsel] + row * 128 + kc * 8);
        f32x4 p0 = src[0], p1 = src[1];
        short8 v;
        v[0] = (short)f2bf(p0[0]); v[1] = (short)f2bf(p0[1]);
        v[2] = (short)f2bf(p0[2]); v[3] = (short)f2bf(p0[3]);
        v[4] = (short)f2bf(p1[0]); v[5] = (short)f2bf(p1[1]);
        v[6] = (short)f2bf(p1[2]); v[7] = (short)f2bf(p1[3]);
        int off = (row * 256 + kc * 16) ^ ((row & 7) << 4);
        *(short8*)(Ld[wsel] + off) = v;
      }
    }
  }
  __syncthreads();

  const int l15 = lane & 15;
  const int g   = lane >> 4;          // 0..3
  const int sx  = (lane & 7) << 4;    // row&7 == lane&7 for all our 16B reads

  float bias1[8], bias2[8];
  #pragma unroll
  for (int jt = 0; jt < 8; ++jt) {
    bias1[jt] = b1[jt * 16 + l15];
    bias2[jt] = b2[jt * 16 + l15];
  }

  float sum8[8] = {0.f,0.f,0.f,0.f,0.f,0.f,0.f,0.f};
  const f32x4 zero4 = {0.f, 0.f, 0.f, 0.f};

  for (int p = 0; p < PASSES; ++p) {
    const int nbase = p * (NBLK * 256) + (int)blockIdx.x * 256 + wid * 32;
    if (nbase >= N_NODES) continue;

    // ---- load x fragments (2 row-tiles x 4 k-tiles), fp32 -> bf16 ----
    short8 a[2][4];
    #pragma unroll
    for (int rt = 0; rt < 2; ++rt) {
      int node = nbase + rt * 16 + l15;
      node = node < N_NODES ? node : (N_NODES - 1);
      const f32x4* xp = (const f32x4*)(x + (size_t)node * 128) + g * 2;
      #pragma unroll
      for (int k0i = 0; k0i < 4; ++k0i) {
        f32x4 p0 = xp[k0i * 8 + 0];
        f32x4 p1 = xp[k0i * 8 + 1];
        short8 v;
        v[0] = (short)f2bf(p0[0]); v[1] = (short)f2bf(p0[1]);
        v[2] = (short)f2bf(p0[2]); v[3] = (short)f2bf(p0[3]);
        v[4] = (short)f2bf(p1[0]); v[5] = (short)f2bf(p1[1]);
        v[6] = (short)f2bf(p1[2]); v[7] = (short)f2bf(p1[3]);
        a[rt][k0i] = v;
      }
    }

    // ---- layer 1: [32 x 128] = X @ W1^T ----
    f32x4 acc0[8], acc1[8];
    #pragma unroll
    for (int jt = 0; jt < 8; ++jt) { acc0[jt] = zero4; acc1[jt] = zero4; }
    #pragma unroll
    for (int k0i = 0; k0i < 4; ++k0i) {
      #pragma unroll
      for (int jt = 0; jt < 8; ++jt) {
        short8 bf = *(const short8*)(ldsW0 +
            ((((jt * 16 + l15) << 8) + k0i * 64 + g * 16) ^ sx));
        acc0[jt] = mfma16(a[0][k0i], bf, acc0[jt]);
        acc1[jt] = mfma16(a[1][k0i], bf, acc1[jt]);
      }
    }

    // ---- epilogue 1: bias+relu, bf16 -> per-wave h1 LDS (swizzled) ----
    #pragma unroll
    for (int rt = 0; rt < 2; ++rt) {
      #pragma unroll
      for (int jt = 0; jt < 8; ++jt) {
        f32x4 v = rt ? acc1[jt] : acc0[jt];
        #pragma unroll
        for (int r = 0; r < 4; ++r) {
          float hv = fmaxf(v[r] + bias1[jt], 0.0f);
          int rl  = rt * 16 + g * 4 + r;
          int off = ((rl << 8) + (jt * 16 + l15) * 2) ^ ((rl & 7) << 4);
          *(unsigned short*)(h1 + off) = f2bf(hv);
        }
      }
    }

    // ---- layer 2 A-fragments from h1 ----
    short8 a2[2][4];
    #pragma unroll
    for (int rt = 0; rt < 2; ++rt)
      #pragma unroll
      for (int k0i = 0; k0i < 4; ++k0i)
        a2[rt][k0i] = *(const short8*)(h1 +
            ((((rt * 16 + l15) << 8) + k0i * 64 + g * 16) ^ sx));

    // ---- layer 2: [32 x 128] = H1 @ W2^T ----
    #pragma unroll
    for (int jt = 0; jt < 8; ++jt) { acc0[jt] = zero4; acc1[jt] = zero4; }
    #pragma unroll
    for (int k0i = 0; k0i < 4; ++k0i) {
      #pragma unroll
      for (int jt = 0; jt < 8; ++jt) {
        short8 bf = *(const short8*)(ldsW1 +
            ((((jt * 16 + l15) << 8) + k0i * 64 + g * 16) ^ sx));
        acc0[jt] = mfma16(a2[0][k0i], bf, acc0[jt]);
        acc1[jt] = mfma16(a2[1][k0i], bf, acc1[jt]);
      }
    }

    // ---- epilogue 2: bias+relu, masked column-sum ----
    #pragma unroll
    for (int rt = 0; rt < 2; ++rt) {
      #pragma unroll
      for (int jt = 0; jt < 8; ++jt) {
        f32x4 v = rt ? acc1[jt] : acc0[jt];
        #pragma unroll
        for (int r = 0; r < 4; ++r) {
          int node = nbase + rt * 16 + g * 4 + r;
          float hv = fmaxf(v[r] + bias2[jt], 0.0f);
          sum8[jt] += (node < N_NODES) ? hv : 0.0f;
        }
      }
    }
  }

  // ---- reduce: lane-groups -> per-wave, waves -> block, block -> global ----
  #pragma unroll
  for (int jt = 0; jt < 8; ++jt) {
    sum8[jt] += __shfl_xor(sum8[jt], 16, 64);
    sum8[jt] += __shfl_xor(sum8[jt], 32, 64);
  }
  __syncthreads();                       // all waves done with h1 area
  float* red = (float*)(lds + 65536);    // reuse h1 area: [8][128]
  if (lane < 16) {
    #pragma unroll
    for (int jt = 0; jt < 8; ++jt) red[wid * 128 + jt * 16 + lane] = sum8[jt];
  }
  __syncthreads();
  if (tid < 128) {
    float t = 0.f;
    #pragma unroll
    for (int w = 0; w < 8; ++w) t += red[w * 128 + tid];
    unsafeAtomicAdd(&sums[tid], t);
  }
}

// mean -> W3 -> classifier -> log_softmax, all fp32, trivial cost
__global__ void gcn_tail(const float* __restrict__ sums,
                         const float* __restrict__ W3, const float* __restrict__ b3,
                         const float* __restrict__ Wl, const float* __restrict__ bl,
                         float* __restrict__ out)
{
  __shared__ float h3[128];
  __shared__ float lg[16];
  int t = threadIdx.x;   // 128 threads
  float acc = 0.f;
  for (int k = 0; k < 128; ++k) acc += sums[k] * W3[t * 128 + k];
  h3[t] = b3[t] + acc * (1.0f / (float)N_NODES);
  __syncthreads();
  if (t < 10) {
    float a = bl[t];
    for (int j = 0; j < 128; ++j) a += h3[j] * Wl[t * 128 + j];
    lg[t] = a;
  }
  __syncthreads();
  if (t == 0) {
    float m = lg[0];
    for (int c = 1; c < 10; ++c) m = fmaxf(m, lg[c]);
    float s = 0.f;
    for (int c = 0; c < 10; ++c) s += expf(lg[c] - m);
    float lse = m + logf(s);
    for (int c = 0; c < 10; ++c) out[c] = lg[c] - lse;
  }
}

extern "C" void kernel_launch(void* const* d_in, const int* in_sizes, int n_in,
                              void* d_out, int out_size, void* d_ws, size_t ws_size,
                              hipStream_t stream) {
  const float* x  = (const float*)d_in[0];
  // d_in[1] = edge_index (int64) — unused: ChebConv K=1 has no propagation
  const float* W1 = (const float*)d_in[2];
  const float* b1 = (const float*)d_in[3];
  const float* W2 = (const float*)d_in[4];
  const float* b2 = (const float*)d_in[5];
  const float* W3 = (const float*)d_in[6];
  const float* b3 = (const float*)d_in[7];
  const float* Wl = (const float*)d_in[8];
  const float* bl = (const float*)d_in[9];
  float* sums = (float*)d_ws;            // 128 floats of scratch
  float* out  = (float*)d_out;           // 10 floats

  hipFuncSetAttribute((const void*)gcn_main,
                      hipFuncAttributeMaxDynamicSharedMemorySize, LDS_BYTES);
  hipMemsetAsync(sums, 0, 128 * sizeof(float), stream);
  gcn_main<<<NBLK, TPB, LDS_BYTES, stream>>>(x, W1, b1, W2, b2, sums);
  gcn_tail<<<1, 128, 0, stream>>>(sums, W3, b3, Wl, bl, out);
}

// Round 2
// 44.782 us; speedup vs baseline: 1.2533x; 1.2533x over previous
//
#include <hip/hip_runtime.h>

#define N_NODES 200000
#define TILE    64
#define NTILES  3125           // 200000 / 64 exactly
#define NBLK    512            // all co-resident at 2 blocks/CU
#define TPB     512            // 8 waves; wave w owns output-feature tile w

typedef __attribute__((ext_vector_type(8))) short short8;   // bf16x8 fragment
typedef __attribute__((ext_vector_type(4))) float f32x4;

__device__ __forceinline__ unsigned short f2bf(float f) {
  unsigned int u = __builtin_bit_cast(unsigned int, f);
  u += 0x7FFFu + ((u >> 16) & 1u);
  return (unsigned short)(u >> 16);
}

__device__ __forceinline__ short8 pack8(f32x4 p0, f32x4 p1) {
  short8 v;
  v[0] = (short)f2bf(p0[0]); v[1] = (short)f2bf(p0[1]);
  v[2] = (short)f2bf(p0[2]); v[3] = (short)f2bf(p0[3]);
  v[4] = (short)f2bf(p1[0]); v[5] = (short)f2bf(p1[1]);
  v[6] = (short)f2bf(p1[2]); v[7] = (short)f2bf(p1[3]);
  return v;
}

__device__ __forceinline__ f32x4 mfma16(short8 a, short8 b, f32x4 c) {
  return __builtin_amdgcn_mfma_f32_16x16x32_bf16(a, b, c, 0, 0, 0);
}

__global__ __launch_bounds__(TPB, 4) void gcn_main(
    const float* __restrict__ x,  const float* __restrict__ W1,
    const float* __restrict__ b1, const float* __restrict__ W2,
    const float* __restrict__ b2, float* __restrict__ sums)
{
  // 48 KB static LDS: double-buffered x tile + shared h1, all bf16 swizzled
  __shared__ char xbuf[2][16384];   // [64 nodes][128 feat] bf16
  __shared__ char h1buf[16384];     // [64 nodes][128 feat] bf16

  const int tid  = threadIdx.x;
  const int lane = tid & 63;
  const int wid  = tid >> 6;        // feature tile jt = wid
  const int l15  = lane & 15;
  const int g    = lane >> 4;       // 0..3
  const int sx   = (l15 & 7) << 4;  // read-side swizzle (row&7 == l15&7)

  // ---- per-wave W fragments in registers (B-operand layout) ----
  const int jrow = wid * 16 + l15;  // output feature / W row
  short8 w1f[4], w2f[4];
  #pragma unroll
  for (int k0i = 0; k0i < 4; ++k0i) {
    const f32x4* p1 = (const f32x4*)(W1 + jrow * 128 + k0i * 32 + g * 8);
    const f32x4* p2 = (const f32x4*)(W2 + jrow * 128 + k0i * 32 + g * 8);
    w1f[k0i] = pack8(p1[0], p1[1]);
    w2f[k0i] = pack8(p2[0], p2[1]);
  }
  const float bias1 = b1[jrow];
  const float bias2 = b2[jrow];

  // ---- contiguous tile range for this block (bijective split) ----
  const int q = NTILES / NBLK, r = NTILES % NBLK;
  const int bid = (int)blockIdx.x;
  const int t0 = bid * q + (bid < r ? bid : r);
  const int t1 = t0 + q + (bid < r ? 1 : 0);

  // staging map: 1024 16B-chunks; thread handles chunks tid and tid+512
  const int row_a = tid >> 4,          kc_a = tid & 15;
  const int row_b = (tid + 512) >> 4,  kc_b = (tid + 512) & 15;
  const int woff_a = row_a * 256 + ((kc_a * 16) ^ ((row_a & 7) << 4));
  const int woff_b = row_b * 256 + ((kc_b * 16) ^ ((row_b & 7) << 4));

  f32x4 gx[4];
  float sum = 0.0f;
  const f32x4 zero4 = {0.f, 0.f, 0.f, 0.f};

#define LOAD_GX(tile)                                                          \
  {                                                                            \
    const float* bx = x + (size_t)(tile) * (TILE * 128);                       \
    const f32x4* sa = (const f32x4*)(bx + row_a * 128 + kc_a * 8);             \
    const f32x4* sb = (const f32x4*)(bx + row_b * 128 + kc_b * 8);             \
    gx[0] = sa[0]; gx[1] = sa[1]; gx[2] = sb[0]; gx[3] = sb[1];                \
  }
#define WRITE_XBUF(buf)                                                        \
  {                                                                            \
    *(short8*)((buf) + woff_a) = pack8(gx[0], gx[1]);                          \
    *(short8*)((buf) + woff_b) = pack8(gx[2], gx[3]);                          \
  }

  // prologue: stage first tile
  LOAD_GX(t0);
  WRITE_XBUF(xbuf[0]);
  __syncthreads();

  int cur = 0;
  for (int t = t0; t < t1; ++t, cur ^= 1) {
    const bool hasnext = (t + 1) < t1;
    if (hasnext) LOAD_GX(t + 1);      // in flight across L1+L2 compute

    // ---- layer 1: [64 x 16] = X-tile @ W1^T(slice wid) ----
    const char* xb = xbuf[cur];
    f32x4 acc[4];
    #pragma unroll
    for (int rt = 0; rt < 4; ++rt) acc[rt] = zero4;
    #pragma unroll
    for (int k0i = 0; k0i < 4; ++k0i) {
      const int co = (((k0i * 4 + g) * 16) ^ sx) + l15 * 256;
      #pragma unroll
      for (int rt = 0; rt < 4; ++rt) {
        short8 af = *(const short8*)(xb + rt * 4096 + co);
        acc[rt] = mfma16(af, w1f[k0i], acc[rt]);
      }
    }

    // ---- epilogue 1: bias + relu -> shared h1 (bf16, swizzled) ----
    #pragma unroll
    for (int rt = 0; rt < 4; ++rt) {
      #pragma unroll
      for (int rr = 0; rr < 4; ++rr) {
        float hv = fmaxf(acc[rt][rr] + bias1, 0.0f);
        int rl = rt * 16 + g * 4 + rr;
        int off = rl * 256 + ((jrow * 2) ^ ((rl & 7) << 4));
        *(unsigned short*)(h1buf + off) = f2bf(hv);
      }
    }
    __syncthreads();                  // h1 ready; xbuf[cur] fully consumed

    // ---- layer 2: [64 x 16] = H1 @ W2^T(slice wid), fused column-sum ----
    #pragma unroll
    for (int rt = 0; rt < 4; ++rt) acc[rt] = zero4;
    #pragma unroll
    for (int k0i = 0; k0i < 4; ++k0i) {
      const int co = (((k0i * 4 + g) * 16) ^ sx) + l15 * 256;
      #pragma unroll
      for (int rt = 0; rt < 4; ++rt) {
        short8 af = *(const short8*)(h1buf + rt * 4096 + co);
        acc[rt] = mfma16(af, w2f[k0i], acc[rt]);
      }
    }
    #pragma unroll
    for (int rt = 0; rt < 4; ++rt) {
      #pragma unroll
      for (int rr = 0; rr < 4; ++rr)
        sum += fmaxf(acc[rt][rr] + bias2, 0.0f);
    }

    // ---- stage next tile into the other buffer ----
    if (hasnext) WRITE_XBUF(xbuf[cur ^ 1]);
    __syncthreads();                  // h1 consumed; next xbuf ready
  }

  // ---- reduce over g-groups (same feature, different nodes) ----
  sum += __shfl_xor(sum, 16, 64);
  sum += __shfl_xor(sum, 32, 64);
  if (g == 0)
    unsafeAtomicAdd(&sums[(bid & 3) * 128 + jrow], sum);
#undef LOAD_GX
#undef WRITE_XBUF
}

// mean -> W3 -> classifier -> log_softmax, fp32, trivial cost
__global__ void gcn_tail(const float* __restrict__ sums,
                         const float* __restrict__ W3, const float* __restrict__ b3,
                         const float* __restrict__ Wl, const float* __restrict__ bl,
                         float* __restrict__ out)
{
  __shared__ float h3[128];
  __shared__ float lg[16];
  int t = threadIdx.x;   // 128 threads
  float m = (sums[t] + sums[128 + t] + sums[256 + t] + sums[384 + t])
            * (1.0f / (float)N_NODES);
  h3[t] = m;
  __syncthreads();
  float accv = 0.f;
  for (int k = 0; k < 128; ++k) accv += h3[k] * W3[t * 128 + k];
  float h3o = b3[t] + accv;
  __syncthreads();
  h3[t] = h3o;
  __syncthreads();
  if (t < 10) {
    float a = bl[t];
    for (int j = 0; j < 128; ++j) a += h3[j] * Wl[t * 128 + j];
    lg[t] = a;
  }
  __syncthreads();
  if (t == 0) {
    float mx = lg[0];
    for (int c = 1; c < 10; ++c) mx = fmaxf(mx, lg[c]);
    float s = 0.f;
    for (int c = 0; c < 10; ++c) s += expf(lg[c] - mx);
    float lse = mx + logf(s);
    for (int c = 0; c < 10; ++c) out[c] = lg[c] - lse;
  }
}

extern "C" void kernel_launch(void* const* d_in, const int* in_sizes, int n_in,
                              void* d_out, int out_size, void* d_ws, size_t ws_size,
                              hipStream_t stream) {
  const float* x  = (const float*)d_in[0];
  // d_in[1] = edge_index (int64) — unused: ChebConv K=1 has no propagation
  const float* W1 = (const float*)d_in[2];
  const float* b1 = (const float*)d_in[3];
  const float* W2 = (const float*)d_in[4];
  const float* b2 = (const float*)d_in[5];
  const float* W3 = (const float*)d_in[6];
  const float* b3 = (const float*)d_in[7];
  const float* Wl = (const float*)d_in[8];
  const float* bl = (const float*)d_in[9];
  float* sums = (float*)d_ws;            // 4 replicas x 128 floats
  float* out  = (float*)d_out;

  hipMemsetAsync(sums, 0, 4 * 128 * sizeof(float), stream);
  gcn_main<<<NBLK, TPB, 0, stream>>>(x, W1, b1, W2, b2, sums);
  gcn_tail<<<1, 128, 0, stream>>>(sums, W3, b3, Wl, bl, out);
}